// Round 1
// baseline (3897.173 us; speedup 1.0000x reference)
//
#include <hip/hip_runtime.h>

using u16 = unsigned short;
using u32 = unsigned int;

#define NPOS   225          // 15*15
#define ROWP   136          // padded LDS row stride (ushorts): 272B, bank stride 4 -> ~conflict-free b128
#define A_ROWS 289          // 17*17 haloed
#define A_ELEMS (A_ROWS*ROWP)            // 39304 ushorts
#define B_ELEMS (NPOS*ROWP)              // 30600 ushorts
#define LDS_BYTES ((A_ELEMS + B_ELEMS)*2)  // 139808 B < 160 KiB

// transposed-weight layout in d_ws (float offsets)
#define W_D0   0        // [6][128]      k=c*3+t
#define W_RD   768      // 4 x [384][128]
#define W_RP   197376   // 4 x [128][128]
#define W_C1   262912   // [128][128]
#define W_C2   279296   // [128][128]
#define W_FIN  295680   // [128][64]
#define W_TOTAL 303872

__device__ __forceinline__ u32 vcomp(const uint4& v, int k){
  switch(k){ case 0: return v.x; case 1: return v.y; case 2: return v.z; default: return v.w; }
}
__device__ __forceinline__ float bflo(u32 q){ return __uint_as_float(q << 16); }
__device__ __forceinline__ float bfhi(u32 q){ return __uint_as_float(q & 0xffff0000u); }
__device__ __forceinline__ u16 f2bf(float f){
  u32 u = __float_as_uint(f);
  return (u16)((u + 0x7fffu + ((u >> 16) & 1u)) >> 16);   // RNE
}
__device__ __forceinline__ u32 packbf(float a, float b){
  return (u32)f2bf(a) | ((u32)f2bf(b) << 16);
}
__device__ __forceinline__ float silu_f(float x){
  return x * __builtin_amdgcn_rcpf(1.f + __expf(-x));
}

// ---- weight transpose/prep into ws ----
__global__ void prep_w(const float* __restrict__ d0w, const float* __restrict__ rdw,
                       const float* __restrict__ rpw, const float* __restrict__ c1w,
                       const float* __restrict__ c2w, const float* __restrict__ fw,
                       float* __restrict__ ws)
{
  for (int idx = blockIdx.x*blockDim.x + threadIdx.x; idx < W_TOTAL; idx += gridDim.x*blockDim.x){
    float v;
    if (idx < W_RD){                       // dconv0: [6][128] <- [128][2][3]
      int k = idx >> 7, o = idx & 127;
      v = d0w[o*6 + k];
    } else if (idx < W_RP){                // res dconv: [384][128] <- [128][128][3]
      int t = idx - W_RD; int L = t / 49152; int r = t % 49152;
      int k = r >> 7, o = r & 127;
      v = rdw[L*49152 + o*384 + k];
    } else if (idx < W_C1){                // res pw: [128][128] <- [128][128]
      int t = idx - W_RP; int L = t / 16384; int r = t % 16384;
      int c = r >> 7, o = r & 127;
      v = rpw[L*16384 + o*128 + c];
    } else if (idx < W_C2){
      int t = idx - W_C1; int c = t >> 7, o = t & 127;
      v = c1w[o*128 + c];
    } else if (idx < W_FIN){
      int t = idx - W_C2; int c = t >> 7, o = t & 127;
      v = c2w[o*128 + c];
    } else {                               // final: [128][64] <- [64][128]
      int t = idx - W_FIN; int c = t / 64, o = t & 63;
      v = fw[o*128 + c];
    }
    ws[idx] = v;
  }
}

// ---- directional conv, 128->128, A(haloed) -> B ----
__device__ __forceinline__ void dconv128(const u16* __restrict__ As, u16* __restrict__ Bs,
    const float* __restrict__ wl, const float* __restrict__ bias,
    int lane, int ob, int off0, int off2)
{
  #pragma unroll 1
  for (int pb = 0; pb < 4; ++pb){
    int p = pb*64 + lane;
    if (p >= NPOS) continue;
    int i = p/15, j = p - i*15;
    int rb = ((i+1)*17 + (j+1))*ROWP;
    const u16* a0 = As + rb + off0;
    const u16* a1 = As + rb;
    const u16* a2 = As + rb + off2;
    float acc[16];
    #pragma unroll
    for (int oo=0;oo<16;++oo) acc[oo] = bias[ob+oo];
    #pragma unroll 1
    for (int c8=0;c8<16;++c8){
      uint4 v0 = *(const uint4*)(a0 + c8*8);
      uint4 v1 = *(const uint4*)(a1 + c8*8);
      uint4 v2 = *(const uint4*)(a2 + c8*8);
      #pragma unroll
      for (int k=0;k<4;++k){
        u32 q0 = vcomp(v0,k), q1 = vcomp(v1,k), q2 = vcomp(v2,k);
        int c = c8*8 + k*2;
        float x0l=bflo(q0), x1l=bflo(q1), x2l=bflo(q2);
        float x0h=bfhi(q0), x1h=bfhi(q1), x2h=bfhi(q2);
        const float* wlo = wl + (c*3    )*128 + ob;   // rows c*3+{0,1,2}
        const float* whi = wl + (c*3 + 3)*128 + ob;   // rows (c+1)*3+{0,1,2}
        #pragma unroll
        for (int oo=0;oo<16;++oo){
          float a = acc[oo];
          a = fmaf(wlo[oo    ], x0l, a);
          a = fmaf(wlo[128+oo], x1l, a);
          a = fmaf(wlo[256+oo], x2l, a);
          a = fmaf(whi[oo    ], x0h, a);
          a = fmaf(whi[128+oo], x1h, a);
          a = fmaf(whi[256+oo], x2h, a);
          acc[oo] = a;
        }
      }
    }
    u16* dp = Bs + p*ROWP + ob;
    #pragma unroll
    for (int oo=0;oo<16;oo+=2)
      *(u32*)(dp+oo) = packbf(silu_f(acc[oo]), silu_f(acc[oo+1]));
  }
}

// ---- pointwise conv 128->128; optional residual-add with in-place dst ----
template<bool HALO_SRC, bool HALO_DST, bool RESID>
__device__ __forceinline__ void pw128(const u16* __restrict__ src, u16* __restrict__ dst,
    const float* __restrict__ wl, const float* __restrict__ bias, int lane, int ob)
{
  #pragma unroll 1
  for (int pb = 0; pb < 4; ++pb){
    int p = pb*64 + lane;
    if (p >= NPOS) continue;
    int i = p/15, j = p - i*15;
    int rs = HALO_SRC ? ((i+1)*17 + (j+1))*ROWP : p*ROWP;
    int rd = HALO_DST ? ((i+1)*17 + (j+1))*ROWP : p*ROWP;
    const u16* s = src + rs;
    float acc[16];
    #pragma unroll
    for (int oo=0;oo<16;++oo) acc[oo] = bias[ob+oo];
    #pragma unroll 1
    for (int c8=0;c8<16;++c8){
      uint4 v = *(const uint4*)(s + c8*8);
      #pragma unroll
      for (int k=0;k<4;++k){
        u32 q = vcomp(v,k);
        int c = c8*8 + k*2;
        float xl = bflo(q), xh = bfhi(q);
        const float* w0 = wl + c*128 + ob;
        const float* w1 = w0 + 128;
        #pragma unroll
        for (int oo=0;oo<16;++oo){
          float a = acc[oo];
          a = fmaf(w0[oo], xl, a);
          a = fmaf(w1[oo], xh, a);
          acc[oo] = a;
        }
      }
    }
    u16* dp = dst + rd + ob;
    #pragma unroll
    for (int oo=0;oo<16;oo+=2){
      float h0 = silu_f(acc[oo]);
      float h1 = silu_f(acc[oo+1]);
      if (RESID){
        u32 r = *(const u32*)(dp+oo);
        h0 += bflo(r); h1 += bfhi(r);
      }
      *(u32*)(dp+oo) = packbf(h0, h1);
    }
  }
}

__global__ void __launch_bounds__(512)
mix9_main(const float* __restrict__ x,
          const float* __restrict__ b_d0,
          const float* __restrict__ b_rd,
          const float* __restrict__ b_rp,
          const float* __restrict__ b_c1,
          const float* __restrict__ b_c2,
          const float* __restrict__ b_fin,
          const float* __restrict__ wt,
          float* __restrict__ out)
{
  extern __shared__ u16 sm[];
  u16* As = sm;              // [289][136] haloed bf16 activations
  u16* Bs = sm + A_ELEMS;    // [225][136] scratch

  const int blk  = blockIdx.x;
  const int b    = blk >> 2, d = blk & 3;
  const int tid  = threadIdx.x;
  const int wave = __builtin_amdgcn_readfirstlane(tid >> 6);
  const int lane = tid & 63;
  const int ob   = wave * 16;

  const int DI0[4] = {0,-1, 1,-1}, DJ0[4] = {-1, 0,-1,-1};
  const int DI2[4] = {0, 1,-1, 1}, DJ2[4] = { 1, 0, 1, 1};
  const int di0 = DI0[d], dj0 = DJ0[d], di2 = DI2[d], dj2 = DJ2[d];
  const int off0 = (di0*17 + dj0)*ROWP;
  const int off2 = (di2*17 + dj2)*ROWP;

  // zero haloed A; stage input image into B-region as fp32
  for (int k2 = tid; k2 < A_ELEMS; k2 += 512) As[k2] = 0;
  float* xs = (float*)Bs;          // 450 floats
  for (int k2 = tid; k2 < 2*NPOS; k2 += 512) xs[k2] = x[b*(2*NPOS) + k2];
  __syncthreads();

  // ---- dconv0: 2 -> 128, from xs -> A ----
  #pragma unroll 1
  for (int pb = 0; pb < 4; ++pb){
    int p = pb*64 + lane;
    if (p >= NPOS) continue;
    int i = p/15, j = p - i*15;
    float acc[16];
    #pragma unroll
    for (int oo=0;oo<16;++oo) acc[oo] = b_d0[ob+oo];
    #pragma unroll
    for (int c=0;c<2;++c){
      int i0=i+di0, j0=j+dj0, i2=i+di2, j2=j+dj2;
      float x0 = ((unsigned)i0<15u && (unsigned)j0<15u) ? xs[c*NPOS + i0*15 + j0] : 0.f;
      float x1 = xs[c*NPOS + p];
      float x2 = ((unsigned)i2<15u && (unsigned)j2<15u) ? xs[c*NPOS + i2*15 + j2] : 0.f;
      const float* w0r = wt + (c*3+0)*128 + ob;
      const float* w1r = wt + (c*3+1)*128 + ob;
      const float* w2r = wt + (c*3+2)*128 + ob;
      #pragma unroll
      for (int oo=0;oo<16;++oo)
        acc[oo] = fmaf(w0r[oo],x0, fmaf(w1r[oo],x1, fmaf(w2r[oo],x2, acc[oo])));
    }
    u16* dp = As + ((i+1)*17 + (j+1))*ROWP + ob;
    #pragma unroll
    for (int oo=0;oo<16;oo+=2)
      *(u32*)(dp+oo) = packbf(silu_f(acc[oo]), silu_f(acc[oo+1]));
  }
  __syncthreads();

  // ---- 4 directional res blocks ----
  #pragma unroll 1
  for (int L = 0; L < 4; ++L){
    dconv128(As, Bs, wt + W_RD + L*49152, b_rd + L*128, lane, ob, off0, off2);
    __syncthreads();
    pw128<false,true,true>(Bs, As, wt + W_RP + L*16384, b_rp + L*128, lane, ob);
    __syncthreads();
  }

  // ---- Conv0d res block ----
  pw128<true,false,false>(As, Bs, wt + W_C1, b_c1, lane, ob);
  __syncthreads();
  pw128<false,true,true>(Bs, As, wt + W_C2, b_c2, lane, ob);
  __syncthreads();

  // ---- final 1x1: 128 -> 64, write global ----
  {
    const int ob8 = wave * 8;
    const float* wl = wt + W_FIN;
    #pragma unroll 1
    for (int pb = 0; pb < 4; ++pb){
      int p = pb*64 + lane;
      if (p >= NPOS) continue;
      int i = p/15, j = p - i*15;
      const u16* s = As + ((i+1)*17 + (j+1))*ROWP;
      float acc[8];
      #pragma unroll
      for (int oo=0;oo<8;++oo) acc[oo] = b_fin[ob8+oo];
      #pragma unroll 1
      for (int c8=0;c8<16;++c8){
        uint4 v = *(const uint4*)(s + c8*8);
        #pragma unroll
        for (int k=0;k<4;++k){
          u32 q = vcomp(v,k);
          int c = c8*8 + k*2;
          float xl = bflo(q), xh = bfhi(q);
          const float* w0 = wl + c*64 + ob8;
          const float* w1 = w0 + 64;
          #pragma unroll
          for (int oo=0;oo<8;++oo){
            float a = acc[oo];
            a = fmaf(w0[oo], xl, a);
            a = fmaf(w1[oo], xh, a);
            acc[oo] = a;
          }
        }
      }
      float* op = out + ((size_t)(b*4 + d)*64 + ob8)*NPOS + p;
      #pragma unroll
      for (int oo=0;oo<8;++oo) op[oo*NPOS] = acc[oo];
    }
  }
}

extern "C" void kernel_launch(void* const* d_in, const int* in_sizes, int n_in,
                              void* d_out, int out_size, void* d_ws, size_t ws_size,
                              hipStream_t stream)
{
  const float* x     = (const float*)d_in[0];
  const float* w_d0  = (const float*)d_in[1];
  const float* b_d0  = (const float*)d_in[2];
  const float* w_rd  = (const float*)d_in[3];
  const float* b_rd  = (const float*)d_in[4];
  const float* w_rp  = (const float*)d_in[5];
  const float* b_rp  = (const float*)d_in[6];
  const float* w_c1  = (const float*)d_in[7];
  const float* b_c1  = (const float*)d_in[8];
  const float* w_c2  = (const float*)d_in[9];
  const float* b_c2  = (const float*)d_in[10];
  const float* w_fin = (const float*)d_in[11];
  const float* b_fin = (const float*)d_in[12];
  float* wt  = (float*)d_ws;
  float* out = (float*)d_out;

  prep_w<<<128, 512, 0, stream>>>(w_d0, w_rd, w_rp, w_c1, w_c2, w_fin, wt);

  // opt into >64KB dynamic LDS (idempotent host-side call; capture-safe)
  (void)hipFuncSetAttribute((const void*)mix9_main,
                            hipFuncAttributeMaxDynamicSharedMemorySize, LDS_BYTES);
  mix9_main<<<1024, 512, LDS_BYTES, stream>>>(x, b_d0, b_rd, b_rp, b_c1, b_c2, b_fin, wt, out);
}

// Round 2
// 268.183 us; speedup vs baseline: 14.5317x; 14.5317x over previous
//
#include <hip/hip_runtime.h>

using u16 = unsigned short;
using u32 = unsigned int;

typedef __bf16 bf16x8 __attribute__((ext_vector_type(8)));
typedef float  f32x4  __attribute__((ext_vector_type(4)));

#define NPOS   225          // 15*15
#define NTIL   15           // 15 position-tiles of 16 -> 240 (tile 14 partial)
#define ROWP   136          // padded LDS row stride in ushorts (272B, 16B-aligned)
#define A_ROWS 289          // 17*17 haloed
#define B_ROWS 241          // 240 used + 1 guard row (tile-14 b128 overread)
#define A_ELEMS (A_ROWS*ROWP)            // 39304 u16
#define B_ELEMS (B_ROWS*ROWP)            // 32776 u16
#define LDS_BYTES ((A_ELEMS + B_ELEMS)*2)  // 144160 B < 160 KiB

// ---- workspace layout ----
// floats [0..768): dconv0 weights transposed [k=c*3+t][o]
// then bf16 (u16) region, offsets in u16 units:
#define WA_PER_L 49152      // per dconv layer: [8 w][3 t][4 kb][64 lane][8]
#define WP_OFF   (4*WA_PER_L)          // 196608 ; 6 x [8 w][4 kb][64][8]
#define WP_PER   16384
#define WF_OFF   (WP_OFF + 6*WP_PER)   // 294912 ; [4 ot][4 kb][64][8]
#define W_U16_TOTAL (WF_OFF + 8192)    // 303104

__device__ __forceinline__ float bflo(u32 q){ return __uint_as_float(q << 16); }
__device__ __forceinline__ float bfhi(u32 q){ return __uint_as_float(q & 0xffff0000u); }
__device__ __forceinline__ u16 f2bf(float f){
  u32 u = __float_as_uint(f);
  return (u16)((u + 0x7fffu + ((u >> 16) & 1u)) >> 16);   // RNE
}
__device__ __forceinline__ u32 packbf(float a, float b){
  return (u32)f2bf(a) | ((u32)f2bf(b) << 16);
}
__device__ __forceinline__ float silu_f(float x){
  return x * __builtin_amdgcn_rcpf(1.f + __expf(-x));
}
__device__ __forceinline__ f32x4 mfma16(bf16x8 a, bf16x8 b, f32x4 c){
  return __builtin_amdgcn_mfma_f32_16x16x32_bf16(a, b, c, 0, 0, 0);
}

// ---- weight prep: fp32 transpose for dconv0 + bf16 per-lane fragment swizzle ----
__global__ void prep_w(const float* __restrict__ d0w, const float* __restrict__ rdw,
                       const float* __restrict__ rpw, const float* __restrict__ c1w,
                       const float* __restrict__ c2w, const float* __restrict__ fw,
                       float* __restrict__ ws)
{
  u16* wsb = (u16*)(ws + 768);
  const int total = 768 + W_U16_TOTAL;
  for (int idx = blockIdx.x*blockDim.x + threadIdx.x; idx < total; idx += gridDim.x*blockDim.x){
    if (idx < 768){                      // dconv0 fp32: [6][128] <- [128][2][3]
      int k = idx >> 7, o = idx & 127;
      ws[idx] = d0w[o*6 + k];
      continue;
    }
    int e = idx - 768;
    float v;
    if (e < WP_OFF){                     // res dconv frags
      int L = e / WA_PER_L, r = e % WA_PER_L;
      int w = r / 6144, r2 = r % 6144;
      int t = r2 >> 11, r3 = r2 & 2047;  // t stride 2048
      int kb = r3 >> 9, r4 = r3 & 511;
      int l = r4 >> 3, j = r4 & 7;
      int o = w*16 + (l & 15);
      int c = kb*32 + ((l >> 4) << 3) + j;
      v = rdw[((L*128 + o)*128 + c)*3 + t];
    } else if (e < WF_OFF){              // pointwise frags (res0..3, c1, c2)
      int t2 = e - WP_OFF;
      int i = t2 / WP_PER, r = t2 % WP_PER;
      int w = r >> 11, r2 = r & 2047;
      int kb = r2 >> 9, r3 = r2 & 511;
      int l = r3 >> 3, j = r3 & 7;
      int o = w*16 + (l & 15);
      int c = kb*32 + ((l >> 4) << 3) + j;
      v = (i < 4) ? rpw[(i*128 + o)*128 + c]
        : (i == 4) ? c1w[o*128 + c] : c2w[o*128 + c];
    } else {                             // final frags
      int e2 = e - WF_OFF;
      int ot = e2 >> 11, r = e2 & 2047;
      int kb = r >> 9, r2 = r & 511;
      int l = r2 >> 3, j = r2 & 7;
      int o = ot*16 + (l & 15);
      int c = kb*32 + ((l >> 4) << 3) + j;
      v = fw[o*128 + c];
    }
    wsb[e] = f2bf(v);
  }
}

// ---- directional conv 128->128 via MFMA: A(haloed) -> B(compact), silu ----
__device__ __forceinline__ void dconv_mfma(const u16* __restrict__ As, u16* __restrict__ Bs,
    const u16* __restrict__ wloc, const float* __restrict__ bias,
    int lane, int ob, int off0, int off2)
{
  const int col = lane & 15, kg = lane >> 4, koff = kg*8;
  bf16x8 wa[3][4];
  #pragma unroll
  for (int t=0;t<3;++t)
    #pragma unroll
    for (int kb=0;kb<4;++kb)
      wa[t][kb] = *(const bf16x8*)(wloc + ((t*4+kb)*64 + lane)*8);
  f32x4 bias4 = *(const f32x4*)(bias + ob + kg*4);
  const int offr[3] = {off0, 0, off2};
  #pragma unroll 1
  for (int tile=0; tile<NTIL; ++tile){
    int p = tile*16 + col;
    int i = p/15, j = p - i*15;
    int rb = ((i+1)*17 + (j+1))*ROWP;
    f32x4 acc = bias4;
    #pragma unroll
    for (int t=0;t<3;++t){
      const u16* s = As + rb + offr[t] + koff;
      #pragma unroll
      for (int kb=0;kb<4;++kb)
        acc = mfma16(wa[t][kb], *(const bf16x8*)(s + kb*32), acc);
    }
    // C/D: row(o) = ob+kg*4+r, col(p) = p -> 4 consecutive channels, one b64 write
    u16* dp = Bs + p*ROWP + ob + kg*4;
    uint2 v; v.x = packbf(silu_f(acc[0]), silu_f(acc[1]));
    v.y = packbf(silu_f(acc[2]), silu_f(acc[3]));
    *(uint2*)dp = v;
  }
}

// ---- pointwise 128->128 via MFMA ----
template<bool SRC_HALO, bool DST_HALO, bool RESID>
__device__ __forceinline__ void pw_mfma(const u16* __restrict__ src, u16* __restrict__ dst,
    const u16* __restrict__ wloc, const float* __restrict__ bias, int lane, int ob)
{
  const int col = lane & 15, kg = lane >> 4, koff = kg*8;
  bf16x8 wp[4];
  #pragma unroll
  for (int kb=0;kb<4;++kb) wp[kb] = *(const bf16x8*)(wloc + (kb*64 + lane)*8);
  f32x4 bias4 = *(const f32x4*)(bias + ob + kg*4);
  #pragma unroll 1
  for (int tile=0; tile<NTIL; ++tile){
    int p = tile*16 + col;
    int i = p/15, j = p - i*15;
    int rsrc = SRC_HALO ? ((i+1)*17 + (j+1))*ROWP : p*ROWP;
    int rdst = DST_HALO ? ((i+1)*17 + (j+1))*ROWP : p*ROWP;
    f32x4 acc = bias4;
    #pragma unroll
    for (int kb=0;kb<4;++kb)
      acc = mfma16(wp[kb], *(const bf16x8*)(src + rsrc + kb*32 + koff), acc);
    u16* dp = dst + rdst + ob + kg*4;
    float s0 = silu_f(acc[0]), s1 = silu_f(acc[1]);
    float s2 = silu_f(acc[2]), s3 = silu_f(acc[3]);
    if (RESID){
      uint2 r = *(const uint2*)dp;       // old value (zero in halo region)
      s0 += bflo(r.x); s1 += bfhi(r.x); s2 += bflo(r.y); s3 += bfhi(r.y);
    }
    if (!DST_HALO || p < NPOS){          // never corrupt A's zero halo
      uint2 v; v.x = packbf(s0, s1); v.y = packbf(s2, s3);
      *(uint2*)dp = v;
    }
  }
}

__global__ void __launch_bounds__(512)
mix9_main(const float* __restrict__ x,
          const float* __restrict__ b_d0,
          const float* __restrict__ b_rd,
          const float* __restrict__ b_rp,
          const float* __restrict__ b_c1,
          const float* __restrict__ b_c2,
          const float* __restrict__ b_fin,
          const float* __restrict__ wt,
          float* __restrict__ out)
{
  extern __shared__ u16 sm[];
  u16* As = sm;              // [289][136] haloed bf16 activations, zero halo
  u16* Bs = sm + A_ELEMS;    // [241][136] compact scratch (240 used)

  const int blk  = blockIdx.x;
  const int b    = blk >> 2, d = blk & 3;
  const int tid  = threadIdx.x;
  const int wave = __builtin_amdgcn_readfirstlane(tid >> 6);
  const int lane = tid & 63;
  const int ob   = wave * 16;
  const int col  = lane & 15, kg = lane >> 4;

  const int DI0[4] = {0,-1, 1,-1}, DJ0[4] = {-1, 0,-1,-1};
  const int DI2[4] = {0, 1,-1, 1}, DJ2[4] = { 1, 0, 1, 1};
  const int di0 = DI0[d], dj0 = DJ0[d], di2 = DI2[d], dj2 = DJ2[d];
  const int off0 = (di0*17 + dj0)*ROWP;
  const int off2 = (di2*17 + dj2)*ROWP;

  // zero haloed A; stage input image into B-region as fp32
  for (int k2 = tid; k2 < A_ELEMS; k2 += 512) As[k2] = 0;
  float* xs = (float*)Bs;          // 450 floats
  for (int k2 = tid; k2 < 2*NPOS; k2 += 512) xs[k2] = x[b*(2*NPOS) + k2];
  __syncthreads();

  // ---- dconv0: 2 -> 128 (tiny K: plain VALU, fp32 weights) -> A ----
  #pragma unroll 1
  for (int pb = 0; pb < 4; ++pb){
    int p = pb*64 + lane;
    if (p >= NPOS) continue;
    int i = p/15, j = p - i*15;
    float acc[16];
    #pragma unroll
    for (int oo=0;oo<16;++oo) acc[oo] = b_d0[ob+oo];
    #pragma unroll
    for (int c=0;c<2;++c){
      int i0=i+di0, j0=j+dj0, i2=i+di2, j2=j+dj2;
      float x0 = ((unsigned)i0<15u && (unsigned)j0<15u) ? xs[c*NPOS + i0*15 + j0] : 0.f;
      float x1 = xs[c*NPOS + p];
      float x2 = ((unsigned)i2<15u && (unsigned)j2<15u) ? xs[c*NPOS + i2*15 + j2] : 0.f;
      const float* w0r = wt + (c*3+0)*128 + ob;
      const float* w1r = wt + (c*3+1)*128 + ob;
      const float* w2r = wt + (c*3+2)*128 + ob;
      #pragma unroll
      for (int oo=0;oo<16;++oo)
        acc[oo] = fmaf(w0r[oo],x0, fmaf(w1r[oo],x1, fmaf(w2r[oo],x2, acc[oo])));
    }
    u16* dp = As + ((i+1)*17 + (j+1))*ROWP + ob;
    #pragma unroll
    for (int oo=0;oo<16;oo+=2)
      *(u32*)(dp+oo) = packbf(silu_f(acc[oo]), silu_f(acc[oo+1]));
  }
  __syncthreads();

  const u16* wsb = (const u16*)(wt + 768);

  // ---- 4 directional res blocks (MFMA) ----
  #pragma unroll 1
  for (int L = 0; L < 4; ++L){
    dconv_mfma(As, Bs, wsb + L*WA_PER_L + wave*6144, b_rd + L*128, lane, ob, off0, off2);
    __syncthreads();
    pw_mfma<false,true,true>(Bs, As, wsb + WP_OFF + L*WP_PER + wave*2048, b_rp + L*128, lane, ob);
    __syncthreads();
  }

  // ---- Conv0d res block ----
  pw_mfma<true,false,false>(As, Bs, wsb + WP_OFF + 4*WP_PER + wave*2048, b_c1, lane, ob);
  __syncthreads();
  pw_mfma<false,true,true>(Bs, As, wsb + WP_OFF + 5*WP_PER + wave*2048, b_c2, lane, ob);
  __syncthreads();

  // ---- final 1x1: 128 -> 64, MFMA, write global fp32 ----
  {
    const int ot = wave & 3;
    const u16* wl = wsb + WF_OFF + ot*2048;
    bf16x8 wf[4];
    #pragma unroll
    for (int kb=0;kb<4;++kb) wf[kb] = *(const bf16x8*)(wl + (kb*64 + lane)*8);
    f32x4 bias4 = *(const f32x4*)(b_fin + ot*16 + kg*4);
    const int t0 = (wave < 4) ? 0 : 8;
    const int t1 = (wave < 4) ? 8 : NTIL;
    const int koff = kg*8;
    #pragma unroll 1
    for (int tile = t0; tile < t1; ++tile){
      int p = tile*16 + col;
      int i = p/15, j = p - i*15;
      int rb = ((i+1)*17 + (j+1))*ROWP;
      f32x4 acc = bias4;
      #pragma unroll
      for (int kb=0;kb<4;++kb)
        acc = mfma16(wf[kb], *(const bf16x8*)(As + rb + kb*32 + koff), acc);
      if (p < NPOS){
        float* op = out + ((size_t)((b*4 + d)*64 + ot*16 + kg*4))*NPOS + p;
        op[0]      = acc[0];
        op[NPOS]   = acc[1];
        op[2*NPOS] = acc[2];
        op[3*NPOS] = acc[3];
      }
    }
  }
}

extern "C" void kernel_launch(void* const* d_in, const int* in_sizes, int n_in,
                              void* d_out, int out_size, void* d_ws, size_t ws_size,
                              hipStream_t stream)
{
  const float* x     = (const float*)d_in[0];
  const float* w_d0  = (const float*)d_in[1];
  const float* b_d0  = (const float*)d_in[2];
  const float* w_rd  = (const float*)d_in[3];
  const float* b_rd  = (const float*)d_in[4];
  const float* w_rp  = (const float*)d_in[5];
  const float* b_rp  = (const float*)d_in[6];
  const float* w_c1  = (const float*)d_in[7];
  const float* b_c1  = (const float*)d_in[8];
  const float* w_c2  = (const float*)d_in[9];
  const float* b_c2  = (const float*)d_in[10];
  const float* w_fin = (const float*)d_in[11];
  const float* b_fin = (const float*)d_in[12];
  float* wt  = (float*)d_ws;
  float* out = (float*)d_out;

  prep_w<<<128, 512, 0, stream>>>(w_d0, w_rd, w_rp, w_c1, w_c2, w_fin, wt);

  (void)hipFuncSetAttribute((const void*)mix9_main,
                            hipFuncAttributeMaxDynamicSharedMemorySize, LDS_BYTES);
  mix9_main<<<1024, 512, LDS_BYTES, stream>>>(x, b_d0, b_rd, b_rp, b_c1, b_c2, b_fin, wt, out);
}

// Round 3
// 239.800 us; speedup vs baseline: 16.2518x; 1.1184x over previous
//
#include <hip/hip_runtime.h>

using u16 = unsigned short;
using u32 = unsigned int;

typedef __bf16 bf16x8 __attribute__((ext_vector_type(8)));
typedef float  f32x4  __attribute__((ext_vector_type(4)));

#define NPOS   225          // 15*15 valid positions
#define NT     15           // position tiles = image rows; p' = i*16 + j (j<15 valid)
#define ROWP   136          // padded LDS row stride in ushorts (272B, 16B-aligned)
#define A_ROWS 289          // 17*17 haloed
#define B_ROWS 241          // 240 p' rows + 1 guard
#define A_ELEMS (A_ROWS*ROWP)            // 39304 u16
#define B_ELEMS (B_ROWS*ROWP)            // 32776 u16
#define LDS_BYTES ((A_ELEMS + B_ELEMS)*2)  // 144160 B < 160 KiB
#define RSTRIDE17 (17*ROWP)              // 2312

// ---- workspace layout ----
// floats [0..768): dconv0 weights transposed [k=c*3+t][o]
// then bf16 (u16) region, offsets in u16 units:
#define WA_PER_L 49152      // per dconv layer: [8 ot][12 f=t*4+kb][64 lane][8]
#define WP_OFF   (4*WA_PER_L)          // 196608 ; 6 x [8 ot][4 kb][64][8]
#define WP_PER   16384
#define WF_OFF   (WP_OFF + 6*WP_PER)   // 294912 ; [4 ot][4 kb][64][8]
#define W_U16_TOTAL (WF_OFF + 8192)    // 303104

__device__ __forceinline__ float bflo(u32 q){ return __uint_as_float(q << 16); }
__device__ __forceinline__ float bfhi(u32 q){ return __uint_as_float(q & 0xffff0000u); }
__device__ __forceinline__ u16 f2bf(float f){
  u32 u = __float_as_uint(f);
  return (u16)((u + 0x7fffu + ((u >> 16) & 1u)) >> 16);   // RNE (prep kernel only)
}
__device__ __forceinline__ u32 packbf(float a, float b){
  union { __bf16 h[2]; u32 u; } r;
  r.h[0] = (__bf16)a; r.h[1] = (__bf16)b;   // native cast -> v_cvt_pk_bf16_f32
  return r.u;
}
__device__ __forceinline__ float silu_f(float x){
  return x * __builtin_amdgcn_rcpf(1.f + __expf(-x));
}
__device__ __forceinline__ f32x4 mfma16(bf16x8 a, bf16x8 b, f32x4 c){
  return __builtin_amdgcn_mfma_f32_16x16x32_bf16(a, b, c, 0, 0, 0);
}

// ---- weight prep: fp32 transpose for dconv0 + bf16 per-lane fragment swizzle ----
__global__ void prep_w(const float* __restrict__ d0w, const float* __restrict__ rdw,
                       const float* __restrict__ rpw, const float* __restrict__ c1w,
                       const float* __restrict__ c2w, const float* __restrict__ fw,
                       float* __restrict__ ws)
{
  u16* wsb = (u16*)(ws + 768);
  const int total = 768 + W_U16_TOTAL;
  for (int idx = blockIdx.x*blockDim.x + threadIdx.x; idx < total; idx += gridDim.x*blockDim.x){
    if (idx < 768){                      // dconv0 fp32: [6][128] <- [128][2][3]
      int k = idx >> 7, o = idx & 127;
      ws[idx] = d0w[o*6 + k];
      continue;
    }
    int e = idx - 768;
    float v;
    if (e < WP_OFF){                     // res dconv frags
      int L = e / WA_PER_L, r = e % WA_PER_L;
      int w = r / 6144, r2 = r % 6144;
      int t = r2 >> 11, r3 = r2 & 2047;  // t stride 2048
      int kb = r3 >> 9, r4 = r3 & 511;
      int l = r4 >> 3, j = r4 & 7;
      int o = w*16 + (l & 15);
      int c = kb*32 + ((l >> 4) << 3) + j;
      v = rdw[((L*128 + o)*128 + c)*3 + t];
    } else if (e < WF_OFF){              // pointwise frags (res0..3, c1, c2)
      int t2 = e - WP_OFF;
      int i = t2 / WP_PER, r = t2 % WP_PER;
      int w = r >> 11, r2 = r & 2047;
      int kb = r2 >> 9, r3 = r2 & 511;
      int l = r3 >> 3, j = r3 & 7;
      int o = w*16 + (l & 15);
      int c = kb*32 + ((l >> 4) << 3) + j;
      v = (i < 4) ? rpw[(i*128 + o)*128 + c]
        : (i == 4) ? c1w[o*128 + c] : c2w[o*128 + c];
    } else {                             // final frags
      int e2 = e - WF_OFF;
      int ot = e2 >> 11, r = e2 & 2047;
      int kb = r >> 9, r2 = r & 511;
      int l = r2 >> 3, j = r2 & 7;
      int o = ot*16 + (l & 15);
      int c = kb*32 + ((l >> 4) << 3) + j;
      v = fw[o*128 + c];
    }
    wsb[e] = f2bf(v);
  }
}

// ---- directional conv 128->128 via MFMA: A(haloed) -> B(compact p' rows) ----
// wave owns o-tiles {2og, 2og+1} (32 channels) and tiles [T0,T1)
__device__ __forceinline__ void dconv_mfma(const u16* __restrict__ As, u16* __restrict__ Bs,
    const u16* __restrict__ wloc, const float* __restrict__ bias,
    int lane, int og, int T0, int T1, int off0, int off2)
{
  const int col = lane & 15, kg = lane >> 4, koff = kg*8;
  bf16x8 wa[2][12];
  #pragma unroll
  for (int ot=0; ot<2; ++ot)
    #pragma unroll
    for (int f=0; f<12; ++f)
      wa[ot][f] = *(const bf16x8*)(wloc + (2*og+ot)*6144 + f*512 + lane*8);
  f32x4 bz0 = *(const f32x4*)(bias + (2*og)*16 + kg*4);
  f32x4 bz1 = *(const f32x4*)(bias + (2*og+1)*16 + kg*4);
  const int c1 = (col+1)*ROWP;
  #pragma unroll 1
  for (int tile=T0; tile<T1; ++tile){
    int rb = (tile+1)*RSTRIDE17 + c1;
    const u16* s0 = As + rb + off0 + koff;
    const u16* s1 = As + rb + koff;
    const u16* s2 = As + rb + off2 + koff;
    f32x4 a0 = bz0, a1 = bz1;
    #pragma unroll
    for (int kb=0; kb<4; ++kb){
      bf16x8 v0 = *(const bf16x8*)(s0 + kb*32);
      bf16x8 v1 = *(const bf16x8*)(s1 + kb*32);
      bf16x8 v2 = *(const bf16x8*)(s2 + kb*32);
      a0 = mfma16(wa[0][kb],   v0, a0); a1 = mfma16(wa[1][kb],   v0, a1);
      a0 = mfma16(wa[0][4+kb], v1, a0); a1 = mfma16(wa[1][4+kb], v1, a1);
      a0 = mfma16(wa[0][8+kb], v2, a0); a1 = mfma16(wa[1][8+kb], v2, a1);
    }
    if (col < 15){
      u16* dp = Bs + (tile*16+col)*ROWP + og*32 + kg*4;
      uint2 w0; w0.x = packbf(silu_f(a0[0]), silu_f(a0[1]));
      w0.y = packbf(silu_f(a0[2]), silu_f(a0[3]));
      *(uint2*)dp = w0;
      uint2 w1; w1.x = packbf(silu_f(a1[0]), silu_f(a1[1]));
      w1.y = packbf(silu_f(a1[2]), silu_f(a1[3]));
      *(uint2*)(dp+16) = w1;
    }
  }
}

// ---- pointwise 128->128 via MFMA ----
template<bool SRC_HALO, bool DST_HALO, bool RESID>
__device__ __forceinline__ void pw_mfma(const u16* __restrict__ src, u16* __restrict__ dst,
    const u16* __restrict__ wloc, const float* __restrict__ bias,
    int lane, int og, int T0, int T1)
{
  const int col = lane & 15, kg = lane >> 4, koff = kg*8;
  bf16x8 wp[2][4];
  #pragma unroll
  for (int ot=0; ot<2; ++ot)
    #pragma unroll
    for (int kb=0; kb<4; ++kb)
      wp[ot][kb] = *(const bf16x8*)(wloc + (2*og+ot)*2048 + kb*512 + lane*8);
  f32x4 bz0 = *(const f32x4*)(bias + (2*og)*16 + kg*4);
  f32x4 bz1 = *(const f32x4*)(bias + (2*og+1)*16 + kg*4);
  const int c1 = (col+1)*ROWP;
  #pragma unroll 1
  for (int tile=T0; tile<T1; ++tile){
    int rsrc = SRC_HALO ? (tile+1)*RSTRIDE17 + c1 : (tile*16+col)*ROWP;
    int rdst = DST_HALO ? (tile+1)*RSTRIDE17 + c1 : (tile*16+col)*ROWP;
    const u16* s = src + rsrc + koff;
    f32x4 a0 = bz0, a1 = bz1;
    #pragma unroll
    for (int kb=0; kb<4; ++kb){
      bf16x8 v = *(const bf16x8*)(s + kb*32);
      a0 = mfma16(wp[0][kb], v, a0);
      a1 = mfma16(wp[1][kb], v, a1);
    }
    if (col < 15){
      u16* dp = dst + rdst + og*32 + kg*4;
      float s0 = silu_f(a0[0]), s1 = silu_f(a0[1]), s2 = silu_f(a0[2]), s3 = silu_f(a0[3]);
      float t0 = silu_f(a1[0]), t1 = silu_f(a1[1]), t2 = silu_f(a1[2]), t3 = silu_f(a1[3]);
      if (RESID){
        uint2 r0 = *(const uint2*)dp;
        uint2 r1 = *(const uint2*)(dp+16);
        s0 += bflo(r0.x); s1 += bfhi(r0.x); s2 += bflo(r0.y); s3 += bfhi(r0.y);
        t0 += bflo(r1.x); t1 += bfhi(r1.x); t2 += bflo(r1.y); t3 += bfhi(r1.y);
      }
      uint2 w0; w0.x = packbf(s0, s1); w0.y = packbf(s2, s3);
      *(uint2*)dp = w0;
      uint2 w1; w1.x = packbf(t0, t1); w1.y = packbf(t2, t3);
      *(uint2*)(dp+16) = w1;
    }
  }
}

__global__ void __launch_bounds__(512, 2)
mix9_main(const float* __restrict__ x,
          const float* __restrict__ b_d0,
          const float* __restrict__ b_rd,
          const float* __restrict__ b_rp,
          const float* __restrict__ b_c1,
          const float* __restrict__ b_c2,
          const float* __restrict__ b_fin,
          const float* __restrict__ wt,
          float* __restrict__ out)
{
  extern __shared__ u16 sm[];
  u16* As = sm;              // [289][136] haloed bf16 activations, zero halo
  u16* Bs = sm + A_ELEMS;    // [241][136] compact p'-row scratch

  const int blk  = blockIdx.x;
  const int b    = blk >> 2, d = blk & 3;
  const int tid  = threadIdx.x;
  const int wave = __builtin_amdgcn_readfirstlane(tid >> 6);
  const int lane = tid & 63;
  const int og   = wave >> 1;        // o-group: o-tiles {2og, 2og+1}
  const int ph   = wave & 1;         // position half
  const int T0   = ph * 8;
  const int T1   = ph ? NT : 8;
  const int ob   = wave * 16;        // dconv0 prologue channel base (old split)

  const int DI0[4] = {0,-1, 1,-1}, DJ0[4] = {-1, 0,-1,-1};
  const int DI2[4] = {0, 1,-1, 1}, DJ2[4] = { 1, 0, 1, 1};
  const int di0 = DI0[d], dj0 = DJ0[d], di2 = DI2[d], dj2 = DJ2[d];
  const int off0 = (di0*17 + dj0)*ROWP;
  const int off2 = (di2*17 + dj2)*ROWP;

  // zero haloed A; stage input image into B-region as fp32
  for (int k2 = tid; k2 < A_ELEMS; k2 += 512) As[k2] = 0;
  float* xs = (float*)Bs;          // 450 floats
  for (int k2 = tid; k2 < 2*NPOS; k2 += 512) xs[k2] = x[b*(2*NPOS) + k2];
  __syncthreads();

  // ---- dconv0: 2 -> 128 (tiny K: plain VALU, fp32 weights) -> A ----
  #pragma unroll 1
  for (int pb = 0; pb < 4; ++pb){
    int pp = pb*64 + lane;           // p' = i*16 + j
    int i = pp >> 4, j = pp & 15;
    if (i >= 15 || j >= 15) continue;
    float acc[16];
    #pragma unroll
    for (int oo=0;oo<16;++oo) acc[oo] = b_d0[ob+oo];
    #pragma unroll
    for (int c=0;c<2;++c){
      int i0=i+di0, j0=j+dj0, i2=i+di2, j2=j+dj2;
      float x0 = ((unsigned)i0<15u && (unsigned)j0<15u) ? xs[c*NPOS + i0*15 + j0] : 0.f;
      float x1 = xs[c*NPOS + i*15 + j];
      float x2 = ((unsigned)i2<15u && (unsigned)j2<15u) ? xs[c*NPOS + i2*15 + j2] : 0.f;
      const float* w0r = wt + (c*3+0)*128 + ob;
      const float* w1r = wt + (c*3+1)*128 + ob;
      const float* w2r = wt + (c*3+2)*128 + ob;
      #pragma unroll
      for (int oo=0;oo<16;++oo)
        acc[oo] = fmaf(w0r[oo],x0, fmaf(w1r[oo],x1, fmaf(w2r[oo],x2, acc[oo])));
    }
    u16* dp = As + ((i+1)*17 + (j+1))*ROWP + ob;
    #pragma unroll
    for (int oo=0;oo<16;oo+=2)
      *(u32*)(dp+oo) = packbf(silu_f(acc[oo]), silu_f(acc[oo+1]));
  }
  __syncthreads();

  const u16* wsb = (const u16*)(wt + 768);

  // ---- 4 directional res blocks (MFMA) ----
  #pragma unroll 1
  for (int L = 0; L < 4; ++L){
    dconv_mfma(As, Bs, wsb + L*WA_PER_L, b_rd + L*128, lane, og, T0, T1, off0, off2);
    __syncthreads();
    pw_mfma<false,true,true>(Bs, As, wsb + WP_OFF + L*WP_PER, b_rp + L*128, lane, og, T0, T1);
    __syncthreads();
  }

  // ---- Conv0d res block ----
  pw_mfma<true,false,false>(As, Bs, wsb + WP_OFF + 4*WP_PER, b_c1, lane, og, T0, T1);
  __syncthreads();
  pw_mfma<false,true,true>(Bs, As, wsb + WP_OFF + 5*WP_PER, b_c2, lane, og, T0, T1);
  __syncthreads();

  // ---- final 1x1: 128 -> 64, MFMA, write global fp32 ----
  {
    const int col = lane & 15, kg = lane >> 4, koff = kg*8;
    const u16* wl = wsb + WF_OFF + og*2048;
    bf16x8 wf[4];
    #pragma unroll
    for (int kb=0;kb<4;++kb) wf[kb] = *(const bf16x8*)(wl + (kb*64 + lane)*8);
    f32x4 bias4 = *(const f32x4*)(b_fin + og*16 + kg*4);
    const int c1 = (col+1)*ROWP;
    #pragma unroll 1
    for (int tile = T0; tile < T1; ++tile){
      int rb = (tile+1)*RSTRIDE17 + c1;
      const u16* s = As + rb + koff;
      f32x4 acc = bias4;
      #pragma unroll
      for (int kb=0;kb<4;++kb)
        acc = mfma16(wf[kb], *(const bf16x8*)(s + kb*32), acc);
      if (col < 15){
        float* op = out + ((size_t)((b*4 + d)*64 + og*16 + kg*4))*NPOS + tile*15 + col;
        op[0]      = acc[0];
        op[NPOS]   = acc[1];
        op[2*NPOS] = acc[2];
        op[3*NPOS] = acc[3];
      }
    }
  }
}

extern "C" void kernel_launch(void* const* d_in, const int* in_sizes, int n_in,
                              void* d_out, int out_size, void* d_ws, size_t ws_size,
                              hipStream_t stream)
{
  const float* x     = (const float*)d_in[0];
  const float* w_d0  = (const float*)d_in[1];
  const float* b_d0  = (const float*)d_in[2];
  const float* w_rd  = (const float*)d_in[3];
  const float* b_rd  = (const float*)d_in[4];
  const float* w_rp  = (const float*)d_in[5];
  const float* b_rp  = (const float*)d_in[6];
  const float* w_c1  = (const float*)d_in[7];
  const float* b_c1  = (const float*)d_in[8];
  const float* w_c2  = (const float*)d_in[9];
  const float* b_c2  = (const float*)d_in[10];
  const float* w_fin = (const float*)d_in[11];
  const float* b_fin = (const float*)d_in[12];
  float* wt  = (float*)d_ws;
  float* out = (float*)d_out;

  prep_w<<<128, 512, 0, stream>>>(w_d0, w_rd, w_rp, w_c1, w_c2, w_fin, wt);

  (void)hipFuncSetAttribute((const void*)mix9_main,
                            hipFuncAttributeMaxDynamicSharedMemorySize, LDS_BYTES);
  mix9_main<<<1024, 512, LDS_BYTES, stream>>>(x, b_d0, b_rd, b_rp, b_c1, b_c2, b_fin, wt, out);
}